// Round 2
// baseline (1743.301 us; speedup 1.0000x reference)
//
#include <hip/hip_runtime.h>
#include <stdint.h>

// ---------------------------------------------------------------------------
// Fused concat-linear: y = x @ W^T + b, x:[8192,4096] f32, W:[12288,4096] f32,
// b:[12288]. Output = 3 chunks of [8192,4096] f32 concatenated flat.
// v3: cast x,W -> bf16 in d_ws, then 256x256-tile bf16 MFMA GEMM with
// READ-AHEAD pipelined phases: ds_reads for phase p+1 issued before phase p's
// MFMA, counted lgkmcnt (LDS analog of T4) so LDS pipe overlaps MFMA pipe.
// 4 barriers/K-tile, 2 counted vmcnt/K-tile. Fallback: 128x128 f32-path.
// ---------------------------------------------------------------------------

typedef __attribute__((ext_vector_type(8))) short short8;   // 8 x bf16 (4 VGPR)
typedef __attribute__((ext_vector_type(4))) float f32x4;    // MFMA C/D

#define BM  256
#define BN  256
#define BKT 64    // K-tile depth in bf16: 8 chunks of 16 B per row

// round-to-nearest-even f32 -> bf16 (bit trick; inputs are finite normals)
__device__ __forceinline__ unsigned short f2bf(float f) {
  union { float f; unsigned u; } v; v.f = f;
  unsigned u = v.u;
  u += 0x7FFFu + ((u >> 16) & 1u);
  return (unsigned short)(u >> 16);
}

__global__ void cast_f32_to_bf16(const float* __restrict__ in,
                                 unsigned short* __restrict__ out, int n8) {
  int i = blockIdx.x * blockDim.x + threadIdx.x;
  if (i >= n8) return;
  const float4* p = (const float4*)in;
  float4 a = p[2 * i + 0];
  float4 b = p[2 * i + 1];
  uint4 o;
  o.x = (unsigned)f2bf(a.x) | ((unsigned)f2bf(a.y) << 16);
  o.y = (unsigned)f2bf(a.z) | ((unsigned)f2bf(a.w) << 16);
  o.z = (unsigned)f2bf(b.x) | ((unsigned)f2bf(b.y) << 16);
  o.w = (unsigned)f2bf(b.z) | ((unsigned)f2bf(b.w) << 16);
  ((uint4*)out)[i] = o;
}

__device__ __forceinline__ void gload16(const unsigned short* src, short* dst) {
  __builtin_amdgcn_global_load_lds(
      (const __attribute__((address_space(1))) unsigned int*)src,
      (__attribute__((address_space(3))) unsigned int*)dst, 16, 0, 0);
}

// ---------------------------------------------------------------------------
// 256x256 read-ahead kernel. 512 threads = 8 waves (2 M x 4 N), each wave owns
// a 128x64 C sub-tile (acc[8][4] f32x4). LDS: 2 dbuf x (A 32KB + B 32KB) =
// 128 KiB -> 1 block/CU, 2 waves/SIMD.
//
// Per K-tile j (buffer P=j&1), 4 phases. Each phase:
//   barrier; stage one 16KB unit; issue ds_reads for the NEXT MFMA group;
//   s_waitcnt lgkmcnt(N) draining only the PREVIOUS group's reads;
//   sched_barrier(0); setprio(1); 16 MFMA; setprio(0)
// Read-ahead schedule (per wave):
//   ph1: issue b23(4)              ; lgkm(4)  ; MFMA1 = acc[0-3][0-1] alo x b01
//   ph2: issue ahi(8)              ; lgkm(8)  ; MFMA2 = acc[0-3][2-3] alo x b23
//   ph3: (none)                    ; lgkm(0)  ; MFMA3 = acc[4-7][2-3] ahi x b23
//        vmcnt(6)   <- drains t(j+1).{Au0,Bu0,Au1} before ph4's reads
//   ph4: issue alo'(8) [t j+1]     ; (no wait); MFMA4 = acc[4-7][0-1] ahi x b01
//        issue b01'(4) AFTER MFMA4 (avoids b01 WAR); vmcnt(4) <- drains t(j+1).Bu1
// Stage schedule: ph1: t(j+1).Bu1 -> P^1; ph2: t(j+2).Au0 -> P;
//                 ph3: t(j+2).Bu0 -> P;   ph4: t(j+2).Au1 -> P.
// Hazards: every staged region's last reads complete before each wave's lgkm
// wait, which precedes its arrival at the phase barrier; stage issues after
// that barrier => >=1 full barrier between last read and overwrite.
// ---------------------------------------------------------------------------
__global__ __launch_bounds__(512, 2)
void gemm256_bias_split(const unsigned short* __restrict__ A,   // [M][K] bf16
                        const unsigned short* __restrict__ B,   // [N][K] bf16
                        const float* __restrict__ bias,         // [N]
                        float* __restrict__ out,                // 3 x [M][H]
                        int M, int N, int K, int H) {
  __shared__ short sA[2][BM * BKT];   // 2 x 32 KiB
  __shared__ short sB[2][BN * BKT];   // 2 x 32 KiB

  const int tid  = threadIdx.x;
  const int lane = tid & 63;
  const int r16  = lane & 15;
  const int q    = lane >> 4;
  const int wave = tid >> 6;
  const int wr   = wave >> 2;          // 0..1
  const int wc   = wave & 3;           // 0..3
  const int AR   = wr * 128;
  const int BR   = wc * 64;

  // XCD-bijective block swizzle (grid here is 1536 = 8*192; guard anyway)
  const int ntx = N / BN;
  int bid = blockIdx.x;
  const int nwg = gridDim.x;
  if ((nwg & 7) == 0) {
    const int cpx = nwg >> 3;
    bid = (bid & 7) * cpx + (bid >> 3);
  }
  const int n0 = (bid % ntx) * BN;
  const int m0 = (bid / ntx) * BM;

  const int NT = K / BKT;

  // ---- staging geometry (per thread): one 16B chunk per issue ----
  const int c   = tid & 7;                       // chunk within row
  const int pr  = tid >> 3;                      // 0..63
  const int csz = c ^ (pr & 7);                  // pre-swizzled source chunk
  const unsigned short* gA = A + (size_t)(m0 + pr) * K + csz * 8;
  const int prB = (pr & 31) + ((tid >> 8) << 6); // B row interleave
  const unsigned short* gB = B + (size_t)(n0 + prB) * K + csz * 8;
  const int dA = pr * 64 + c * 8;                // shorts into sA[buf]
  const int dB = prB * 64 + c * 8;
  const size_t K128 = (size_t)128 * K;

  auto stageA = [&](int buf, int kt, int u) {    // unit u: rows {64u.., 128+64u..}
    const unsigned short* s = gA + (size_t)(u * 64) * K + kt * BKT;
    short* d = &sA[buf][dA + u * 4096];
    gload16(s, d);
    gload16(s + K128, d + 8192);
  };
  auto stageB = [&](int buf, int kt, int u) {    // unit u: rows {32u + 64k ..}
    const unsigned short* s = gB + (size_t)(u * 32) * K + kt * BKT;
    short* d = &sB[buf][dB + u * 2048];
    gload16(s, d);
    gload16(s + K128, d + 8192);
  };

  // ---- ds_read geometry: frag(row = base + f*16 + r16, chunk = ks*4 + q),
  //      chunk XOR-unswizzled by (row&7) == (r16&7) ----
  const int swz  = r16 & 7;
  const int aoff = (AR + r16) * 64;
  const int boff = (BR + r16) * 64;
  const int ck0  = (q ^ swz) * 8;                // ks=0
  const int ck1  = ((4 + q) ^ swz) * 8;          // ks=1

  f32x4 acc[8][4];
#pragma unroll
  for (int i = 0; i < 8; ++i)
#pragma unroll
    for (int j = 0; j < 4; ++j) acc[i][j] = (f32x4){0.f, 0.f, 0.f, 0.f};

  // ---- prologue: stream t0.{Au0,Bu0,Au1,Bu1}, t1.{Au0,Bu0,Au1} ----
  stageA(0, 0, 0); stageB(0, 0, 0); stageA(0, 0, 1); stageB(0, 0, 1);
  stageA(1, 1, 0); stageB(1, 1, 0); stageA(1, 1, 1);
  asm volatile("s_waitcnt vmcnt(6)" ::: "memory");   // t0 fully landed
  __builtin_amdgcn_s_barrier();

  short8 alo[4][2], ahi[4][2], b01[2][2], b23[2][2];

  // "ph4(-1)": initial alo,b01 reads from buffer 0 (tile 0)
#pragma unroll
  for (int mf = 0; mf < 4; ++mf) {
    alo[mf][0] = *(const short8*)&sA[0][aoff + mf * 1024 + ck0];
    alo[mf][1] = *(const short8*)&sA[0][aoff + mf * 1024 + ck1];
  }
#pragma unroll
  for (int nf = 0; nf < 2; ++nf) {
    b01[nf][0] = *(const short8*)&sB[0][boff + nf * 1024 + ck0];
    b01[nf][1] = *(const short8*)&sB[0][boff + nf * 1024 + ck1];
  }

  for (int j = 0; j < NT; ++j) {
    const int P = j & 1;
    const short* bA  = sA[P];
    const short* bB  = sB[P];
    const short* bA1 = sA[P ^ 1];
    const short* bB1 = sB[P ^ 1];

    // ===== phase 1: stage t(j+1).Bu1 ; issue b23 ; MFMA (alo x b01) =====
    __builtin_amdgcn_s_barrier();
    if (j + 1 < NT) stageB(P ^ 1, j + 1, 1);
#pragma unroll
    for (int nf = 0; nf < 2; ++nf) {
      b23[nf][0] = *(const short8*)&bB[boff + (nf + 2) * 1024 + ck0];
      b23[nf][1] = *(const short8*)&bB[boff + (nf + 2) * 1024 + ck1];
    }
    asm volatile("s_waitcnt lgkmcnt(4)" ::: "memory");  // alo,b01 done; b23 in flight
    __builtin_amdgcn_sched_barrier(0);
    __builtin_amdgcn_s_setprio(1);
#pragma unroll
    for (int mf = 0; mf < 4; ++mf)
#pragma unroll
      for (int nf = 0; nf < 2; ++nf) {
        acc[mf][nf] = __builtin_amdgcn_mfma_f32_16x16x32_bf16(alo[mf][0], b01[nf][0], acc[mf][nf], 0, 0, 0);
        acc[mf][nf] = __builtin_amdgcn_mfma_f32_16x16x32_bf16(alo[mf][1], b01[nf][1], acc[mf][nf], 0, 0, 0);
      }
    __builtin_amdgcn_s_setprio(0);

    // ===== phase 2: stage t(j+2).Au0 ; issue ahi ; MFMA (alo x b23) =====
    __builtin_amdgcn_s_barrier();
    if (j + 2 < NT) stageA(P, j + 2, 0);
#pragma unroll
    for (int mf = 0; mf < 4; ++mf) {
      ahi[mf][0] = *(const short8*)&bA[aoff + (mf + 4) * 1024 + ck0];
      ahi[mf][1] = *(const short8*)&bA[aoff + (mf + 4) * 1024 + ck1];
    }
    asm volatile("s_waitcnt lgkmcnt(8)" ::: "memory");  // b23 done; ahi in flight
    __builtin_amdgcn_sched_barrier(0);
    __builtin_amdgcn_s_setprio(1);
#pragma unroll
    for (int mf = 0; mf < 4; ++mf)
#pragma unroll
      for (int nf = 0; nf < 2; ++nf) {
        acc[mf][nf + 2] = __builtin_amdgcn_mfma_f32_16x16x32_bf16(alo[mf][0], b23[nf][0], acc[mf][nf + 2], 0, 0, 0);
        acc[mf][nf + 2] = __builtin_amdgcn_mfma_f32_16x16x32_bf16(alo[mf][1], b23[nf][1], acc[mf][nf + 2], 0, 0, 0);
      }
    __builtin_amdgcn_s_setprio(0);

    // ===== phase 3: stage t(j+2).Bu0 ; MFMA (ahi x b23) ; vmcnt(6) =====
    __builtin_amdgcn_s_barrier();
    if (j + 2 < NT) stageB(P, j + 2, 0);
    asm volatile("s_waitcnt lgkmcnt(0)" ::: "memory");  // ahi done
    __builtin_amdgcn_sched_barrier(0);
    __builtin_amdgcn_s_setprio(1);
#pragma unroll
    for (int mf = 0; mf < 4; ++mf)
#pragma unroll
      for (int nf = 0; nf < 2; ++nf) {
        acc[mf + 4][nf + 2] = __builtin_amdgcn_mfma_f32_16x16x32_bf16(ahi[mf][0], b23[nf][0], acc[mf + 4][nf + 2], 0, 0, 0);
        acc[mf + 4][nf + 2] = __builtin_amdgcn_mfma_f32_16x16x32_bf16(ahi[mf][1], b23[nf][1], acc[mf + 4][nf + 2], 0, 0, 0);
      }
    __builtin_amdgcn_s_setprio(0);
    // drain t(j+1).{Au0,Bu0,Au1} (its Bu1 + t(j+2).{Au0,Bu0} stay in flight)
    if (j < NT - 2) asm volatile("s_waitcnt vmcnt(6)" ::: "memory");
    else            asm volatile("s_waitcnt vmcnt(0)" ::: "memory");

    // ===== phase 4: stage t(j+2).Au1 ; issue alo'(t j+1) ; MFMA (ahi x b01) =====
    __builtin_amdgcn_s_barrier();
    if (j + 2 < NT) stageA(P, j + 2, 1);
    if (j + 1 < NT) {
#pragma unroll
      for (int mf = 0; mf < 4; ++mf) {
        alo[mf][0] = *(const short8*)&bA1[aoff + mf * 1024 + ck0];
        alo[mf][1] = *(const short8*)&bA1[aoff + mf * 1024 + ck1];
      }
    }
    __builtin_amdgcn_sched_barrier(0);                  // keep alo' issue above MFMA4
    __builtin_amdgcn_s_setprio(1);
#pragma unroll
    for (int mf = 0; mf < 4; ++mf)
#pragma unroll
      for (int nf = 0; nf < 2; ++nf) {
        acc[mf + 4][nf] = __builtin_amdgcn_mfma_f32_16x16x32_bf16(ahi[mf][0], b01[nf][0], acc[mf + 4][nf], 0, 0, 0);
        acc[mf + 4][nf] = __builtin_amdgcn_mfma_f32_16x16x32_bf16(ahi[mf][1], b01[nf][1], acc[mf + 4][nf], 0, 0, 0);
      }
    __builtin_amdgcn_s_setprio(0);
    if (j + 1 < NT) {                                   // b01' AFTER MFMA4 (WAR-safe)
#pragma unroll
      for (int nf = 0; nf < 2; ++nf) {
        b01[nf][0] = *(const short8*)&bB1[boff + nf * 1024 + ck0];
        b01[nf][1] = *(const short8*)&bB1[boff + nf * 1024 + ck1];
      }
    }
    // drain t(j+1).Bu1 before next ph1's b23 reads
    if (j < NT - 2) asm volatile("s_waitcnt vmcnt(4)" ::: "memory");
    else            asm volatile("s_waitcnt vmcnt(0)" ::: "memory");
  }

  // ---- epilogue: +bias, write into concat-split layout ----
  // C/D layout: col(n) = lane&15, row(m) = (lane>>4)*4 + reg   [m89/m91]
  float bj[4];
#pragma unroll
  for (int nf = 0; nf < 4; ++nf) bj[nf] = bias[n0 + BR + nf * 16 + r16];
  const size_t chunk_elems = (size_t)M * H;
#pragma unroll
  for (int nf = 0; nf < 4; ++nf) {
    const int n  = n0 + BR + nf * 16 + r16;
    const int ci = n / H;                    // which of the 3 output chunks
    const int h  = n - ci * H;
    float* obase = out + (size_t)ci * chunk_elems + h;
#pragma unroll
    for (int mf = 0; mf < 8; ++mf) {
      const int mb = m0 + AR + mf * 16 + q * 4;
#pragma unroll
      for (int rr = 0; rr < 4; ++rr) {
        obase[(size_t)(mb + rr) * H] = acc[mf][nf][rr] + bj[nf];
      }
    }
  }
}

// ---------------------------------------------------------------------------
// Fallback (no workspace / odd shapes): 128x128 kernel, f32 inputs staged via
// VGPR round-trip with inline f32->bf16.
// ---------------------------------------------------------------------------
#define FTILE 128
#define FBK   64

__global__ __launch_bounds__(256)
void gemm_bias_split_fb(const float* __restrict__ Af32,
                        const float* __restrict__ Bf32,
                        const float* __restrict__ bias,
                        float* __restrict__ out,
                        int M, int N, int K, int H) {
  __shared__ short sA[FTILE * FBK];
  __shared__ short sB[FTILE * FBK];

  const int tid  = threadIdx.x;
  const int lane = tid & 63;
  const int r16  = lane & 15;
  const int q    = lane >> 4;
  const int wave = tid >> 6;
  const int wm   = (wave & 1) * 64;
  const int wn   = (wave >> 1) * 64;
  const int m0   = blockIdx.y * FTILE;
  const int n0   = blockIdx.x * FTILE;

  f32x4 acc[4][4];
#pragma unroll
  for (int i = 0; i < 4; ++i)
#pragma unroll
    for (int j = 0; j < 4; ++j)
      acc[i][j] = (f32x4){0.f, 0.f, 0.f, 0.f};

  for (int k0 = 0; k0 < K; k0 += FBK) {
    __syncthreads();
#pragma unroll
    for (int it = 0; it < 4; ++it) {
      const int chunk = it * 256 + tid;
      const int row   = chunk >> 3;
      const int c     = chunk & 7;
      const int cs    = c ^ (row & 7);
      const float* gA = Af32 + (size_t)(m0 + row) * K + (k0 + cs * 8);
      const float* gB = Bf32 + (size_t)(n0 + row) * K + (k0 + cs * 8);
      float4 a0 = ((const float4*)gA)[0], a1 = ((const float4*)gA)[1];
      float4 b0 = ((const float4*)gB)[0], b1 = ((const float4*)gB)[1];
      short8 va, vb;
      va[0] = (short)f2bf(a0.x); va[1] = (short)f2bf(a0.y);
      va[2] = (short)f2bf(a0.z); va[3] = (short)f2bf(a0.w);
      va[4] = (short)f2bf(a1.x); va[5] = (short)f2bf(a1.y);
      va[6] = (short)f2bf(a1.z); va[7] = (short)f2bf(a1.w);
      vb[0] = (short)f2bf(b0.x); vb[1] = (short)f2bf(b0.y);
      vb[2] = (short)f2bf(b0.z); vb[3] = (short)f2bf(b0.w);
      vb[4] = (short)f2bf(b1.x); vb[5] = (short)f2bf(b1.y);
      vb[6] = (short)f2bf(b1.z); vb[7] = (short)f2bf(b1.w);
      *(short8*)&sA[chunk * 8] = va;
      *(short8*)&sB[chunk * 8] = vb;
    }
    __syncthreads();

#pragma unroll
    for (int ks = 0; ks < 2; ++ks) {
      short8 af[4], bfr[4];
#pragma unroll
      for (int i = 0; i < 4; ++i) {
        const int row = wm + i * 16 + r16;
        const int cc  = ks * 4 + q;
        af[i] = *(const short8*)&sA[row * FBK + (cc ^ (row & 7)) * 8];
      }
#pragma unroll
      for (int j = 0; j < 4; ++j) {
        const int row = wn + j * 16 + r16;
        const int cc  = ks * 4 + q;
        bfr[j] = *(const short8*)&sB[row * FBK + (cc ^ (row & 7)) * 8];
      }
#pragma unroll
      for (int i = 0; i < 4; ++i)
#pragma unroll
        for (int j = 0; j < 4; ++j)
          acc[i][j] = __builtin_amdgcn_mfma_f32_16x16x32_bf16(
              af[i], bfr[j], acc[i][j], 0, 0, 0);
    }
  }

  float bj[4];
#pragma unroll
  for (int j = 0; j < 4; ++j) bj[j] = bias[n0 + wn + j * 16 + r16];
  const size_t chunk_elems = (size_t)M * H;
#pragma unroll
  for (int j = 0; j < 4; ++j) {
    const int n  = n0 + wn + j * 16 + r16;
    const int ci = n / H;
    const int h  = n - ci * H;
    float* obase = out + (size_t)ci * chunk_elems + h;
#pragma unroll
    for (int i = 0; i < 4; ++i) {
      const int mb = m0 + wm + i * 16 + q * 4;
#pragma unroll
      for (int rr = 0; rr < 4; ++rr) {
        obase[(size_t)(mb + rr) * H] = acc[i][j][rr] + bj[j];
      }
    }
  }
}

extern "C" void kernel_launch(void* const* d_in, const int* in_sizes, int n_in,
                              void* d_out, int out_size, void* d_ws, size_t ws_size,
                              hipStream_t stream) {
  const float* x = (const float*)d_in[0];
  const float* W = (const float*)d_in[1];
  const float* b = (const float*)d_in[2];
  float* out = (float*)d_out;

  const int N = in_sizes[2];                 // 12288
  const int K = in_sizes[1] / N;             // 4096
  const int M = in_sizes[0] / K;             // 8192 (= 4*2048)
  const int H = N / 3;                       // 4096

  const size_t nA = (size_t)M * K;
  const size_t nB = (size_t)N * K;
  const bool ws_ok = ws_size >= (nA + nB) * sizeof(unsigned short);
  const bool big   = ws_ok && (M % BM == 0) && (N % BN == 0) &&
                     (K % BKT == 0) && (K / BKT >= 4);

  if (big) {
    unsigned short* xa = (unsigned short*)d_ws;
    unsigned short* wb = xa + nA;
    cast_f32_to_bf16<<<(int)((nA / 8 + 255) / 256), 256, 0, stream>>>(x, xa, (int)(nA / 8));
    cast_f32_to_bf16<<<(int)((nB / 8 + 255) / 256), 256, 0, stream>>>(W, wb, (int)(nB / 8));
    const int nblocks = (M / BM) * (N / BN); // 32 * 48 = 1536
    gemm256_bias_split<<<nblocks, 512, 0, stream>>>(xa, wb, b, out, M, N, K, H);
  } else {
    dim3 grid(N / FTILE, M / FTILE);
    gemm_bias_split_fb<<<grid, 256, 0, stream>>>(x, W, b, out, M, N, K, H);
  }
}

// Round 3
// 1566.284 us; speedup vs baseline: 1.1130x; 1.1130x over previous
//
#include <hip/hip_runtime.h>
#include <stdint.h>

// ---------------------------------------------------------------------------
// Fused concat-linear: y = x @ W^T + b, x:[8192,4096] f32, W:[12288,4096] f32,
// b:[12288]. Output = 3 chunks of [8192,4096] f32 concatenated flat.
// v4: v2's proven 2-barrier lockstep 256x256 structure + intra-phase split
// lgkm waits (first-half MFMA overlaps the tail of the LDS read burst),
// need-ordered ds_reads pinned with sched_barrier, pre-barrier lgkm drain
// hint on the 12-read phase, merged cast kernel (one launch).
// ---------------------------------------------------------------------------

typedef __attribute__((ext_vector_type(8))) short short8;   // 8 x bf16 (4 VGPR)
typedef __attribute__((ext_vector_type(4))) float f32x4;    // MFMA C/D

#define BM  256
#define BN  256
#define BKT 64    // K-tile depth in bf16: 8 chunks of 16 B per row

// round-to-nearest-even f32 -> bf16 (bit trick; inputs are finite normals)
__device__ __forceinline__ unsigned short f2bf(float f) {
  union { float f; unsigned u; } v; v.f = f;
  unsigned u = v.u;
  u += 0x7FFFu + ((u >> 16) & 1u);
  return (unsigned short)(u >> 16);
}

// one launch casts both x and W (saves a launch + tail bubble)
__global__ void cast2_f32_to_bf16(const float* __restrict__ inA,
                                  unsigned short* __restrict__ outA, long long nA8,
                                  const float* __restrict__ inB,
                                  unsigned short* __restrict__ outB, long long nB8) {
  long long i = (long long)blockIdx.x * blockDim.x + threadIdx.x;
  const float* in; unsigned short* out; long long k;
  if (i < nA8) { in = inA; out = outA; k = i; }
  else {
    k = i - nA8;
    if (k >= nB8) return;
    in = inB; out = outB;
  }
  const float4* p = (const float4*)in;
  float4 a = p[2 * k + 0];
  float4 b = p[2 * k + 1];
  uint4 o;
  o.x = (unsigned)f2bf(a.x) | ((unsigned)f2bf(a.y) << 16);
  o.y = (unsigned)f2bf(a.z) | ((unsigned)f2bf(a.w) << 16);
  o.z = (unsigned)f2bf(b.x) | ((unsigned)f2bf(b.y) << 16);
  o.w = (unsigned)f2bf(b.z) | ((unsigned)f2bf(b.w) << 16);
  ((uint4*)out)[k] = o;
}

__device__ __forceinline__ void gload16(const unsigned short* src, short* dst) {
  __builtin_amdgcn_global_load_lds(
      (const __attribute__((address_space(1))) unsigned int*)src,
      (__attribute__((address_space(3))) unsigned int*)dst, 16, 0, 0);
}

// ---------------------------------------------------------------------------
// 256x256 kernel. 512 threads = 8 waves (2 M x 4 N), each wave owns a 128x64
// C sub-tile (acc[8][4] f32x4). LDS: 2 dbuf x (A 32KB + B 32KB) = 128 KiB.
//
// Per K-tile j (buffer P=j&1), 4 phases, each: {stage 1 unit; issue ds_reads
// in need-order; barrier; lgkm(N) -> first-half MFMA (8); lgkm(0) ->
// second-half MFMA (8); barrier}. Split waits let the read-burst tail overlap
// the first MFMA half. Read groups pinned with sched_barrier(0) so the
// counted lgkm values match issue order (DS completes in-order).
//   ph1: stage t(j+1).Bu1 ; reads b01(4),alo01(4) | alo23(4) ; MFMA m0-3 x n0-1
//   ph2: stage t(j+2).Au0 ; reads b23[0](2) | b23[1](2)      ; MFMA m0-3 x n2-3
//   ph3: stage t(j+2).Bu0 ; reads ahi01(4) | ahi23(4)        ; MFMA m4-7 x n2-3
//   ph4: stage t(j+2).Au1 ; no reads                          ; MFMA m4-7 x n0-1
//        vmcnt(6) at tile end: steady-state outstanding = 14 (t(j+1) 8 +
//        t(j+2) 6); drains exactly the 8 oldest = all of tile j+1. Same
//        ledger as v2 (proven).
// ---------------------------------------------------------------------------
__global__ __launch_bounds__(512, 2)
void gemm256_bias_split(const unsigned short* __restrict__ A,   // [M][K] bf16
                        const unsigned short* __restrict__ B,   // [N][K] bf16
                        const float* __restrict__ bias,         // [N]
                        float* __restrict__ out,                // 3 x [M][H]
                        int M, int N, int K, int H) {
  __shared__ short sA[2][BM * BKT];   // 2 x 32 KiB
  __shared__ short sB[2][BN * BKT];   // 2 x 32 KiB

  const int tid  = threadIdx.x;
  const int lane = tid & 63;
  const int r16  = lane & 15;
  const int q    = lane >> 4;
  const int wave = tid >> 6;
  const int wr   = wave >> 2;          // 0..1
  const int wc   = wave & 3;           // 0..3
  const int AR   = wr * 128;
  const int BR   = wc * 64;

  // XCD-bijective block swizzle (grid here is 1536 = 8*192; guard anyway)
  const int ntx = N / BN;
  int bid = blockIdx.x;
  const int nwg = gridDim.x;
  if ((nwg & 7) == 0) {
    const int cpx = nwg >> 3;
    bid = (bid & 7) * cpx + (bid >> 3);
  }
  const int n0 = (bid % ntx) * BN;
  const int m0 = (bid / ntx) * BM;

  const int NT = K / BKT;

  // ---- staging geometry (per thread): one 16B chunk per issue ----
  const int c   = tid & 7;                       // chunk within row
  const int pr  = tid >> 3;                      // 0..63
  const int csz = c ^ (pr & 7);                  // pre-swizzled source chunk
  const unsigned short* gA = A + (size_t)(m0 + pr) * K + csz * 8;
  const int prB = (pr & 31) + ((tid >> 8) << 6); // B row interleave
  const unsigned short* gB = B + (size_t)(n0 + prB) * K + csz * 8;
  const int dA = pr * 64 + c * 8;                // shorts into sA[buf]
  const int dB = prB * 64 + c * 8;
  const size_t K128 = (size_t)128 * K;

  auto stageA = [&](int buf, int kt, int u) {    // unit u: rows {64u.., 128+64u..}
    const unsigned short* s = gA + (size_t)(u * 64) * K + kt * BKT;
    short* d = &sA[buf][dA + u * 4096];
    gload16(s, d);
    gload16(s + K128, d + 8192);
  };
  auto stageB = [&](int buf, int kt, int u) {    // unit u: rows {32u + 64k ..}
    const unsigned short* s = gB + (size_t)(u * 32) * K + kt * BKT;
    short* d = &sB[buf][dB + u * 2048];
    gload16(s, d);
    gload16(s + K128, d + 8192);
  };

  // ---- ds_read geometry: frag(row = base + f*16 + r16, chunk = ks*4 + q),
  //      chunk XOR-unswizzled by (row&7) == (r16&7) ----
  const int swz  = r16 & 7;
  const int aoff = (AR + r16) * 64;
  const int boff = (BR + r16) * 64;
  const int ck0  = (q ^ swz) * 8;                // ks=0
  const int ck1  = ((4 + q) ^ swz) * 8;          // ks=1

  f32x4 acc[8][4];
#pragma unroll
  for (int i = 0; i < 8; ++i)
#pragma unroll
    for (int j = 0; j < 4; ++j) acc[i][j] = (f32x4){0.f, 0.f, 0.f, 0.f};

  // ---- prologue: stream t0.{Au0,Bu0,Au1,Bu1}, t1.{Au0,Bu0,Au1} ----
  stageA(0, 0, 0); stageB(0, 0, 0); stageA(0, 0, 1); stageB(0, 0, 1);
  stageA(1, 1, 0); stageB(1, 1, 0); stageA(1, 1, 1);
  asm volatile("s_waitcnt vmcnt(6)" ::: "memory");   // t0 fully landed
  __builtin_amdgcn_s_barrier();

  short8 alo[4][2], ahi[4][2], b01[2][2], b23[2][2];

  for (int j = 0; j < NT; ++j) {
    const int P = j & 1;
    const short* bA = sA[P];
    const short* bB = sB[P];

    // ===== phase 1: stage t(j+1).Bu1 ; reads b01,alo01 | alo23 =====
    if (j + 1 < NT) stageB(P ^ 1, j + 1, 1);
#pragma unroll
    for (int nf = 0; nf < 2; ++nf) {
      b01[nf][0] = *(const short8*)&bB[boff + nf * 1024 + ck0];
      b01[nf][1] = *(const short8*)&bB[boff + nf * 1024 + ck1];
    }
#pragma unroll
    for (int mf = 0; mf < 2; ++mf) {
      alo[mf][0] = *(const short8*)&bA[aoff + mf * 1024 + ck0];
      alo[mf][1] = *(const short8*)&bA[aoff + mf * 1024 + ck1];
    }
    __builtin_amdgcn_sched_barrier(0);                // group1 (8) before group2
#pragma unroll
    for (int mf = 2; mf < 4; ++mf) {
      alo[mf][0] = *(const short8*)&bA[aoff + mf * 1024 + ck0];
      alo[mf][1] = *(const short8*)&bA[aoff + mf * 1024 + ck1];
    }
    asm volatile("s_waitcnt lgkmcnt(8)" ::: "memory"); // pre-barrier drain hint
    __builtin_amdgcn_s_barrier();
    asm volatile("s_waitcnt lgkmcnt(4)" ::: "memory"); // b01 + alo[0..1] ready
    __builtin_amdgcn_sched_barrier(0);
    __builtin_amdgcn_s_setprio(1);
#pragma unroll
    for (int mf = 0; mf < 2; ++mf)
#pragma unroll
      for (int nf = 0; nf < 2; ++nf) {
        acc[mf][nf] = __builtin_amdgcn_mfma_f32_16x16x32_bf16(alo[mf][0], b01[nf][0], acc[mf][nf], 0, 0, 0);
        acc[mf][nf] = __builtin_amdgcn_mfma_f32_16x16x32_bf16(alo[mf][1], b01[nf][1], acc[mf][nf], 0, 0, 0);
      }
    asm volatile("s_waitcnt lgkmcnt(0)" ::: "memory"); // alo[2..3] ready
    __builtin_amdgcn_sched_barrier(0);
#pragma unroll
    for (int mf = 2; mf < 4; ++mf)
#pragma unroll
      for (int nf = 0; nf < 2; ++nf) {
        acc[mf][nf] = __builtin_amdgcn_mfma_f32_16x16x32_bf16(alo[mf][0], b01[nf][0], acc[mf][nf], 0, 0, 0);
        acc[mf][nf] = __builtin_amdgcn_mfma_f32_16x16x32_bf16(alo[mf][1], b01[nf][1], acc[mf][nf], 0, 0, 0);
      }
    __builtin_amdgcn_s_setprio(0);
    __builtin_amdgcn_s_barrier();

    // ===== phase 2: stage t(j+2).Au0 ; reads b23[0] | b23[1] =====
    if (j + 2 < NT) stageA(P, j + 2, 0);
    b23[0][0] = *(const short8*)&bB[boff + 2 * 1024 + ck0];
    b23[0][1] = *(const short8*)&bB[boff + 2 * 1024 + ck1];
    __builtin_amdgcn_sched_barrier(0);
    b23[1][0] = *(const short8*)&bB[boff + 3 * 1024 + ck0];
    b23[1][1] = *(const short8*)&bB[boff + 3 * 1024 + ck1];
    __builtin_amdgcn_s_barrier();
    asm volatile("s_waitcnt lgkmcnt(2)" ::: "memory"); // b23[0] ready
    __builtin_amdgcn_sched_barrier(0);
    __builtin_amdgcn_s_setprio(1);
#pragma unroll
    for (int mf = 0; mf < 4; ++mf) {
      acc[mf][2] = __builtin_amdgcn_mfma_f32_16x16x32_bf16(alo[mf][0], b23[0][0], acc[mf][2], 0, 0, 0);
      acc[mf][2] = __builtin_amdgcn_mfma_f32_16x16x32_bf16(alo[mf][1], b23[0][1], acc[mf][2], 0, 0, 0);
    }
    asm volatile("s_waitcnt lgkmcnt(0)" ::: "memory"); // b23[1] ready
    __builtin_amdgcn_sched_barrier(0);
#pragma unroll
    for (int mf = 0; mf < 4; ++mf) {
      acc[mf][3] = __builtin_amdgcn_mfma_f32_16x16x32_bf16(alo[mf][0], b23[1][0], acc[mf][3], 0, 0, 0);
      acc[mf][3] = __builtin_amdgcn_mfma_f32_16x16x32_bf16(alo[mf][1], b23[1][1], acc[mf][3], 0, 0, 0);
    }
    __builtin_amdgcn_s_setprio(0);
    __builtin_amdgcn_s_barrier();

    // ===== phase 3: stage t(j+2).Bu0 ; reads ahi01 | ahi23 =====
    if (j + 2 < NT) stageB(P, j + 2, 0);
#pragma unroll
    for (int mf = 0; mf < 2; ++mf) {
      ahi[mf][0] = *(const short8*)&bA[aoff + (mf + 4) * 1024 + ck0];
      ahi[mf][1] = *(const short8*)&bA[aoff + (mf + 4) * 1024 + ck1];
    }
    __builtin_amdgcn_sched_barrier(0);
#pragma unroll
    for (int mf = 2; mf < 4; ++mf) {
      ahi[mf][0] = *(const short8*)&bA[aoff + (mf + 4) * 1024 + ck0];
      ahi[mf][1] = *(const short8*)&bA[aoff + (mf + 4) * 1024 + ck1];
    }
    __builtin_amdgcn_s_barrier();
    asm volatile("s_waitcnt lgkmcnt(4)" ::: "memory"); // ahi[0..1] ready
    __builtin_amdgcn_sched_barrier(0);
    __builtin_amdgcn_s_setprio(1);
#pragma unroll
    for (int mf = 0; mf < 2; ++mf)
#pragma unroll
      for (int nf = 0; nf < 2; ++nf) {
        acc[mf + 4][nf + 2] = __builtin_amdgcn_mfma_f32_16x16x32_bf16(ahi[mf][0], b23[nf][0], acc[mf + 4][nf + 2], 0, 0, 0);
        acc[mf + 4][nf + 2] = __builtin_amdgcn_mfma_f32_16x16x32_bf16(ahi[mf][1], b23[nf][1], acc[mf + 4][nf + 2], 0, 0, 0);
      }
    asm volatile("s_waitcnt lgkmcnt(0)" ::: "memory"); // ahi[2..3] ready
    __builtin_amdgcn_sched_barrier(0);
#pragma unroll
    for (int mf = 2; mf < 4; ++mf)
#pragma unroll
      for (int nf = 0; nf < 2; ++nf) {
        acc[mf + 4][nf + 2] = __builtin_amdgcn_mfma_f32_16x16x32_bf16(ahi[mf][0], b23[nf][0], acc[mf + 4][nf + 2], 0, 0, 0);
        acc[mf + 4][nf + 2] = __builtin_amdgcn_mfma_f32_16x16x32_bf16(ahi[mf][1], b23[nf][1], acc[mf + 4][nf + 2], 0, 0, 0);
      }
    __builtin_amdgcn_s_setprio(0);
    __builtin_amdgcn_s_barrier();

    // ===== phase 4: stage t(j+2).Au1 ; MFMA m4-7 x n0-1 ; vmcnt =====
    if (j + 2 < NT) stageA(P, j + 2, 1);
    __builtin_amdgcn_s_barrier();
    __builtin_amdgcn_s_setprio(1);
#pragma unroll
    for (int mf = 0; mf < 4; ++mf)
#pragma unroll
      for (int nf = 0; nf < 2; ++nf) {
        acc[mf + 4][nf] = __builtin_amdgcn_mfma_f32_16x16x32_bf16(ahi[mf][0], b01[nf][0], acc[mf + 4][nf], 0, 0, 0);
        acc[mf + 4][nf] = __builtin_amdgcn_mfma_f32_16x16x32_bf16(ahi[mf][1], b01[nf][1], acc[mf + 4][nf], 0, 0, 0);
      }
    __builtin_amdgcn_s_setprio(0);
    if (j < NT - 2) asm volatile("s_waitcnt vmcnt(6)" ::: "memory");
    else            asm volatile("s_waitcnt vmcnt(0)" ::: "memory");
    __builtin_amdgcn_s_barrier();
  }

  // ---- epilogue: +bias, write into concat-split layout ----
  // C/D layout: col(n) = lane&15, row(m) = (lane>>4)*4 + reg   [m89/m91]
  float bj[4];
#pragma unroll
  for (int nf = 0; nf < 4; ++nf) bj[nf] = bias[n0 + BR + nf * 16 + r16];
  const size_t chunk_elems = (size_t)M * H;
#pragma unroll
  for (int nf = 0; nf < 4; ++nf) {
    const int n  = n0 + BR + nf * 16 + r16;
    const int ci = n / H;                    // which of the 3 output chunks
    const int h  = n - ci * H;
    float* obase = out + (size_t)ci * chunk_elems + h;
#pragma unroll
    for (int mf = 0; mf < 8; ++mf) {
      const int mb = m0 + AR + mf * 16 + q * 4;
#pragma unroll
      for (int rr = 0; rr < 4; ++rr) {
        obase[(size_t)(mb + rr) * H] = acc[mf][nf][rr] + bj[nf];
      }
    }
  }
}

// ---------------------------------------------------------------------------
// Fallback (no workspace / odd shapes): 128x128 kernel, f32 inputs staged via
// VGPR round-trip with inline f32->bf16.
// ---------------------------------------------------------------------------
#define FTILE 128
#define FBK   64

__global__ __launch_bounds__(256)
void gemm_bias_split_fb(const float* __restrict__ Af32,
                        const float* __restrict__ Bf32,
                        const float* __restrict__ bias,
                        float* __restrict__ out,
                        int M, int N, int K, int H) {
  __shared__ short sA[FTILE * FBK];
  __shared__ short sB[FTILE * FBK];

  const int tid  = threadIdx.x;
  const int lane = tid & 63;
  const int r16  = lane & 15;
  const int q    = lane >> 4;
  const int wave = tid >> 6;
  const int wm   = (wave & 1) * 64;
  const int wn   = (wave >> 1) * 64;
  const int m0   = blockIdx.y * FTILE;
  const int n0   = blockIdx.x * FTILE;

  f32x4 acc[4][4];
#pragma unroll
  for (int i = 0; i < 4; ++i)
#pragma unroll
    for (int j = 0; j < 4; ++j)
      acc[i][j] = (f32x4){0.f, 0.f, 0.f, 0.f};

  for (int k0 = 0; k0 < K; k0 += FBK) {
    __syncthreads();
#pragma unroll
    for (int it = 0; it < 4; ++it) {
      const int chunk = it * 256 + tid;
      const int row   = chunk >> 3;
      const int c     = chunk & 7;
      const int cs    = c ^ (row & 7);
      const float* gA = Af32 + (size_t)(m0 + row) * K + (k0 + cs * 8);
      const float* gB = Bf32 + (size_t)(n0 + row) * K + (k0 + cs * 8);
      float4 a0 = ((const float4*)gA)[0], a1 = ((const float4*)gA)[1];
      float4 b0 = ((const float4*)gB)[0], b1 = ((const float4*)gB)[1];
      short8 va, vb;
      va[0] = (short)f2bf(a0.x); va[1] = (short)f2bf(a0.y);
      va[2] = (short)f2bf(a0.z); va[3] = (short)f2bf(a0.w);
      va[4] = (short)f2bf(a1.x); va[5] = (short)f2bf(a1.y);
      va[6] = (short)f2bf(a1.z); va[7] = (short)f2bf(a1.w);
      vb[0] = (short)f2bf(b0.x); vb[1] = (short)f2bf(b0.y);
      vb[2] = (short)f2bf(b0.z); vb[3] = (short)f2bf(b0.w);
      vb[4] = (short)f2bf(b1.x); vb[5] = (short)f2bf(b1.y);
      vb[6] = (short)f2bf(b1.z); vb[7] = (short)f2bf(b1.w);
      *(short8*)&sA[chunk * 8] = va;
      *(short8*)&sB[chunk * 8] = vb;
    }
    __syncthreads();

#pragma unroll
    for (int ks = 0; ks < 2; ++ks) {
      short8 af[4], bfr[4];
#pragma unroll
      for (int i = 0; i < 4; ++i) {
        const int row = wm + i * 16 + r16;
        const int cc  = ks * 4 + q;
        af[i] = *(const short8*)&sA[row * FBK + (cc ^ (row & 7)) * 8];
      }
#pragma unroll
      for (int j = 0; j < 4; ++j) {
        const int row = wn + j * 16 + r16;
        const int cc  = ks * 4 + q;
        bfr[j] = *(const short8*)&sB[row * FBK + (cc ^ (row & 7)) * 8];
      }
#pragma unroll
      for (int i = 0; i < 4; ++i)
#pragma unroll
        for (int j = 0; j < 4; ++j)
          acc[i][j] = __builtin_amdgcn_mfma_f32_16x16x32_bf16(
              af[i], bfr[j], acc[i][j], 0, 0, 0);
    }
  }

  float bj[4];
#pragma unroll
  for (int j = 0; j < 4; ++j) bj[j] = bias[n0 + wn + j * 16 + r16];
  const size_t chunk_elems = (size_t)M * H;
#pragma unroll
  for (int j = 0; j < 4; ++j) {
    const int n  = n0 + wn + j * 16 + r16;
    const int ci = n / H;
    const int h  = n - ci * H;
    float* obase = out + (size_t)ci * chunk_elems + h;
#pragma unroll
    for (int i = 0; i < 4; ++i) {
      const int mb = m0 + wm + i * 16 + q * 4;
#pragma unroll
      for (int rr = 0; rr < 4; ++rr) {
        obase[(size_t)(mb + rr) * H] = acc[i][j][rr] + bj[j];
      }
    }
  }
}

extern "C" void kernel_launch(void* const* d_in, const int* in_sizes, int n_in,
                              void* d_out, int out_size, void* d_ws, size_t ws_size,
                              hipStream_t stream) {
  const float* x = (const float*)d_in[0];
  const float* W = (const float*)d_in[1];
  const float* b = (const float*)d_in[2];
  float* out = (float*)d_out;

  const int N = in_sizes[2];                 // 12288
  const int K = in_sizes[1] / N;             // 4096
  const int M = in_sizes[0] / K;             // 8192 (= 4*2048)
  const int H = N / 3;                       // 4096

  const size_t nA = (size_t)M * K;
  const size_t nB = (size_t)N * K;
  const bool ws_ok = ws_size >= (nA + nB) * sizeof(unsigned short);
  const bool big   = ws_ok && (M % BM == 0) && (N % BN == 0) &&
                     (K % BKT == 0) && (K / BKT >= 4);

  if (big) {
    unsigned short* xa = (unsigned short*)d_ws;
    unsigned short* wb = xa + nA;
    const long long nA8 = (long long)(nA / 8);
    const long long nB8 = (long long)(nB / 8);
    const long long tot = nA8 + nB8;
    cast2_f32_to_bf16<<<(int)((tot + 255) / 256), 256, 0, stream>>>(
        x, xa, nA8, W, wb, nB8);
    const int nblocks = (M / BM) * (N / BN); // 32 * 48 = 1536
    gemm256_bias_split<<<nblocks, 512, 0, stream>>>(xa, wb, b, out, M, N, K, H);
  } else {
    dim3 grid(N / FTILE, M / FTILE);
    gemm_bias_split_fb<<<grid, 256, 0, stream>>>(x, W, b, out, M, N, K, H);
  }
}

// Round 4
// 1405.362 us; speedup vs baseline: 1.2405x; 1.1145x over previous
//
#include <hip/hip_runtime.h>
#include <stdint.h>

// ---------------------------------------------------------------------------
// Fused concat-linear: y = x @ W^T + b, x:[8192,4096] f32, W:[12288,4096] f32,
// b:[12288]. Output = 3 chunks of [8192,4096] f32 concatenated flat.
// v5: v2's proven 256x256 2-barrier lockstep schedule (947us, byte-identical
// K-loop) + two-level L2-cooperative block swizzle: XCD = bid&7, then
// column-major over the XCD's 4 m-panels so each XCD's ~32 concurrent blocks
// form a 4m x 8n panel window (A shared 8-way, B shared 4-way in L2; B panels
// shared across all 8 XCDs via L3). Attacks the measured staging-supply bound
// (6.8 TB/s beyond-L2 = 5918 cyc/K-tile pace). Merged cast launch.
// ---------------------------------------------------------------------------

typedef __attribute__((ext_vector_type(8))) short short8;   // 8 x bf16 (4 VGPR)
typedef __attribute__((ext_vector_type(4))) float f32x4;    // MFMA C/D

#define BM  256
#define BN  256
#define BKT 64    // K-tile depth in bf16: 8 chunks of 16 B per row

// round-to-nearest-even f32 -> bf16 (bit trick; inputs are finite normals)
__device__ __forceinline__ unsigned short f2bf(float f) {
  union { float f; unsigned u; } v; v.f = f;
  unsigned u = v.u;
  u += 0x7FFFu + ((u >> 16) & 1u);
  return (unsigned short)(u >> 16);
}

// one launch casts both x and W (saves a launch + tail bubble)
__global__ void cast2_f32_to_bf16(const float* __restrict__ inA,
                                  unsigned short* __restrict__ outA, long long nA8,
                                  const float* __restrict__ inB,
                                  unsigned short* __restrict__ outB, long long nB8) {
  long long i = (long long)blockIdx.x * blockDim.x + threadIdx.x;
  const float* in; unsigned short* out; long long k;
  if (i < nA8) { in = inA; out = outA; k = i; }
  else {
    k = i - nA8;
    if (k >= nB8) return;
    in = inB; out = outB;
  }
  const float4* p = (const float4*)in;
  float4 a = p[2 * k + 0];
  float4 b = p[2 * k + 1];
  uint4 o;
  o.x = (unsigned)f2bf(a.x) | ((unsigned)f2bf(a.y) << 16);
  o.y = (unsigned)f2bf(a.z) | ((unsigned)f2bf(a.w) << 16);
  o.z = (unsigned)f2bf(b.x) | ((unsigned)f2bf(b.y) << 16);
  o.w = (unsigned)f2bf(b.z) | ((unsigned)f2bf(b.w) << 16);
  ((uint4*)out)[k] = o;
}

__device__ __forceinline__ void gload16(const unsigned short* src, short* dst) {
  __builtin_amdgcn_global_load_lds(
      (const __attribute__((address_space(1))) unsigned int*)src,
      (__attribute__((address_space(3))) unsigned int*)dst, 16, 0, 0);
}

// ---------------------------------------------------------------------------
// 256x256 kernel (v2 schedule, unchanged). 512 threads = 8 waves (2M x 4N),
// each wave owns a 128x64 C sub-tile (acc[8][4] f32x4). LDS: 128 KiB.
// Per K-tile j (buffer P=j&1), 4 phases, each {reads; stage 1 unit; barrier;
// lgkm(0); setprio(1); 16 MFMA; setprio(0); barrier}; vmcnt(6) at tile end
// drains exactly tile j+1's 8 loads (14 outstanding max). Proven @947us.
// ---------------------------------------------------------------------------
__global__ __launch_bounds__(512, 2)
void gemm256_bias_split(const unsigned short* __restrict__ A,   // [M][K] bf16
                        const unsigned short* __restrict__ B,   // [N][K] bf16
                        const float* __restrict__ bias,         // [N]
                        float* __restrict__ out,                // 3 x [M][H]
                        int M, int N, int K, int H) {
  __shared__ short sA[2][BM * BKT];   // 2 x 32 KiB
  __shared__ short sB[2][BN * BKT];   // 2 x 32 KiB

  const int tid  = threadIdx.x;
  const int lane = tid & 63;
  const int r16  = lane & 15;
  const int q    = lane >> 4;
  const int wave = tid >> 6;
  const int wr   = wave >> 2;          // 0..1
  const int wc   = wave & 3;           // 0..3
  const int AR   = wr * 128;
  const int BR   = wc * 64;

  // ---- two-level L2-cooperative swizzle ----
  // Level 1: XCD = bid&7 (consecutive blockIdx round-robin across XCDs).
  // Level 2: within the XCD's chunk of GM m-panels x ntx n-panels, order
  // column-major over m so ~32 concurrent blocks = GM x (32/GM) panel window.
  const int ntx = N / BN;
  const int nwg = gridDim.x;
  const int mty = nwg / ntx;
  int bid = blockIdx.x;
  int m0, n0;
  if ((nwg & 7) == 0 && (mty & 7) == 0) {
    const int GM  = mty >> 3;          // m-panels per XCD (4 here)
    const int xcd = bid & 7;
    const int l   = bid >> 3;          // local index within XCD chunk
    const int lm  = l % GM;
    const int ln  = l / GM;            // 0..ntx-1
    m0 = (xcd * GM + lm) * BM;
    n0 = ln * BN;
  } else if ((nwg & 7) == 0) {
    const int cpx = nwg >> 3;
    const int b2  = (bid & 7) * cpx + (bid >> 3);
    n0 = (b2 % ntx) * BN;
    m0 = (b2 / ntx) * BM;
  } else {
    n0 = (bid % ntx) * BN;
    m0 = (bid / ntx) * BM;
  }

  const int NT = K / BKT;

  // ---- staging geometry (per thread): one 16B chunk per issue ----
  const int c   = tid & 7;                       // chunk within row
  const int pr  = tid >> 3;                      // 0..63
  const int csz = c ^ (pr & 7);                  // pre-swizzled source chunk
  const unsigned short* gA = A + (size_t)(m0 + pr) * K + csz * 8;
  const int prB = (pr & 31) + ((tid >> 8) << 6); // B row interleave
  const unsigned short* gB = B + (size_t)(n0 + prB) * K + csz * 8;
  const int dA = pr * 64 + c * 8;                // shorts into sA[buf]
  const int dB = prB * 64 + c * 8;
  const size_t K128 = (size_t)128 * K;

  auto stageA = [&](int buf, int kt, int u) {    // unit u: rows {64u.., 128+64u..}
    const unsigned short* s = gA + (size_t)(u * 64) * K + kt * BKT;
    short* d = &sA[buf][dA + u * 4096];
    gload16(s, d);
    gload16(s + K128, d + 8192);
  };
  auto stageB = [&](int buf, int kt, int u) {    // unit u: rows {32u + 64k ..}
    const unsigned short* s = gB + (size_t)(u * 32) * K + kt * BKT;
    short* d = &sB[buf][dB + u * 2048];
    gload16(s, d);
    gload16(s + K128, d + 8192);
  };

  // ---- ds_read geometry: frag(row = base + f*16 + r16, chunk = ks*4 + q),
  //      chunk XOR-unswizzled by (row&7) == (r16&7) ----
  const int swz  = r16 & 7;
  const int aoff = (AR + r16) * 64;
  const int boff = (BR + r16) * 64;
  const int ck0  = (q ^ swz) * 8;                // ks=0
  const int ck1  = ((4 + q) ^ swz) * 8;          // ks=1

  f32x4 acc[8][4];
#pragma unroll
  for (int i = 0; i < 8; ++i)
#pragma unroll
    for (int j = 0; j < 4; ++j) acc[i][j] = (f32x4){0.f, 0.f, 0.f, 0.f};

  // ---- prologue: stream t0.{Au0,Bu0,Au1,Bu1}, t1.{Au0,Bu0,Au1} ----
  stageA(0, 0, 0); stageB(0, 0, 0); stageA(0, 0, 1); stageB(0, 0, 1);
  stageA(1, 1, 0); stageB(1, 1, 0); stageA(1, 1, 1);
  asm volatile("s_waitcnt vmcnt(6)" ::: "memory");   // t0 fully landed
  __builtin_amdgcn_s_barrier();

  short8 alo[4][2], ahi[4][2], b01[2][2], b23[2][2];

  for (int j = 0; j < NT; ++j) {
    const int P = j & 1;
    const short* bA = sA[P];
    const short* bB = sB[P];

    // ===== phase 1: read A m0-3 + B n0-1 ; stage (j+1).Bu1 =====
#pragma unroll
    for (int mf = 0; mf < 4; ++mf) {
      alo[mf][0] = *(const short8*)&bA[aoff + mf * 1024 + ck0];
      alo[mf][1] = *(const short8*)&bA[aoff + mf * 1024 + ck1];
    }
#pragma unroll
    for (int nf = 0; nf < 2; ++nf) {
      b01[nf][0] = *(const short8*)&bB[boff + nf * 1024 + ck0];
      b01[nf][1] = *(const short8*)&bB[boff + nf * 1024 + ck1];
    }
    if (j + 1 < NT) stageB(P ^ 1, j + 1, 1);
    __builtin_amdgcn_s_barrier();
    asm volatile("s_waitcnt lgkmcnt(0)" ::: "memory");
    __builtin_amdgcn_sched_barrier(0);
    __builtin_amdgcn_s_setprio(1);
#pragma unroll
    for (int mf = 0; mf < 4; ++mf)
#pragma unroll
      for (int nf = 0; nf < 2; ++nf) {
        acc[mf][nf] = __builtin_amdgcn_mfma_f32_16x16x32_bf16(alo[mf][0], b01[nf][0], acc[mf][nf], 0, 0, 0);
        acc[mf][nf] = __builtin_amdgcn_mfma_f32_16x16x32_bf16(alo[mf][1], b01[nf][1], acc[mf][nf], 0, 0, 0);
      }
    __builtin_amdgcn_s_setprio(0);
    __builtin_amdgcn_s_barrier();

    // ===== phase 2: read B n2-3 ; stage (j+2).Au0 =====
#pragma unroll
    for (int nf = 0; nf < 2; ++nf) {
      b23[nf][0] = *(const short8*)&bB[boff + (nf + 2) * 1024 + ck0];
      b23[nf][1] = *(const short8*)&bB[boff + (nf + 2) * 1024 + ck1];
    }
    if (j + 2 < NT) stageA(P, j + 2, 0);
    __builtin_amdgcn_s_barrier();
    asm volatile("s_waitcnt lgkmcnt(0)" ::: "memory");
    __builtin_amdgcn_sched_barrier(0);
    __builtin_amdgcn_s_setprio(1);
#pragma unroll
    for (int mf = 0; mf < 4; ++mf)
#pragma unroll
      for (int nf = 0; nf < 2; ++nf) {
        acc[mf][nf + 2] = __builtin_amdgcn_mfma_f32_16x16x32_bf16(alo[mf][0], b23[nf][0], acc[mf][nf + 2], 0, 0, 0);
        acc[mf][nf + 2] = __builtin_amdgcn_mfma_f32_16x16x32_bf16(alo[mf][1], b23[nf][1], acc[mf][nf + 2], 0, 0, 0);
      }
    __builtin_amdgcn_s_setprio(0);
    __builtin_amdgcn_s_barrier();

    // ===== phase 3: read A m4-7 ; stage (j+2).Bu0 =====
#pragma unroll
    for (int mf = 0; mf < 4; ++mf) {
      ahi[mf][0] = *(const short8*)&bA[aoff + (mf + 4) * 1024 + ck0];
      ahi[mf][1] = *(const short8*)&bA[aoff + (mf + 4) * 1024 + ck1];
    }
    if (j + 2 < NT) stageB(P, j + 2, 0);
    __builtin_amdgcn_s_barrier();
    asm volatile("s_waitcnt lgkmcnt(0)" ::: "memory");
    __builtin_amdgcn_sched_barrier(0);
    __builtin_amdgcn_s_setprio(1);
#pragma unroll
    for (int mf = 0; mf < 4; ++mf)
#pragma unroll
      for (int nf = 0; nf < 2; ++nf) {
        acc[mf + 4][nf + 2] = __builtin_amdgcn_mfma_f32_16x16x32_bf16(ahi[mf][0], b23[nf][0], acc[mf + 4][nf + 2], 0, 0, 0);
        acc[mf + 4][nf + 2] = __builtin_amdgcn_mfma_f32_16x16x32_bf16(ahi[mf][1], b23[nf][1], acc[mf + 4][nf + 2], 0, 0, 0);
      }
    __builtin_amdgcn_s_setprio(0);
    __builtin_amdgcn_s_barrier();

    // ===== phase 4: stage (j+2).Au1 ; MFMA (m4-7 x n0-1) ; vmcnt(6) =====
    if (j + 2 < NT) stageA(P, j + 2, 1);
    __builtin_amdgcn_s_barrier();
    __builtin_amdgcn_s_setprio(1);
#pragma unroll
    for (int mf = 0; mf < 4; ++mf)
#pragma unroll
      for (int nf = 0; nf < 2; ++nf) {
        acc[mf + 4][nf] = __builtin_amdgcn_mfma_f32_16x16x32_bf16(ahi[mf][0], b01[nf][0], acc[mf + 4][nf], 0, 0, 0);
        acc[mf + 4][nf] = __builtin_amdgcn_mfma_f32_16x16x32_bf16(ahi[mf][1], b01[nf][1], acc[mf + 4][nf], 0, 0, 0);
      }
    __builtin_amdgcn_s_setprio(0);
    if (j < NT - 2) asm volatile("s_waitcnt vmcnt(6)" ::: "memory");
    else            asm volatile("s_waitcnt vmcnt(0)" ::: "memory");
    __builtin_amdgcn_s_barrier();
  }

  // ---- epilogue: +bias, write into concat-split layout ----
  // C/D layout: col(n) = lane&15, row(m) = (lane>>4)*4 + reg   [m89/m91]
  float bj[4];
#pragma unroll
  for (int nf = 0; nf < 4; ++nf) bj[nf] = bias[n0 + BR + nf * 16 + r16];
  const size_t chunk_elems = (size_t)M * H;
#pragma unroll
  for (int nf = 0; nf < 4; ++nf) {
    const int n  = n0 + BR + nf * 16 + r16;
    const int ci = n / H;                    // which of the 3 output chunks
    const int h  = n - ci * H;
    float* obase = out + (size_t)ci * chunk_elems + h;
#pragma unroll
    for (int mf = 0; mf < 8; ++mf) {
      const int mb = m0 + AR + mf * 16 + q * 4;
#pragma unroll
      for (int rr = 0; rr < 4; ++rr) {
        obase[(size_t)(mb + rr) * H] = acc[mf][nf][rr] + bj[nf];
      }
    }
  }
}

// ---------------------------------------------------------------------------
// Fallback (no workspace / odd shapes): 128x128 kernel, f32 inputs staged via
// VGPR round-trip with inline f32->bf16.
// ---------------------------------------------------------------------------
#define FTILE 128
#define FBK   64

__global__ __launch_bounds__(256)
void gemm_bias_split_fb(const float* __restrict__ Af32,
                        const float* __restrict__ Bf32,
                        const float* __restrict__ bias,
                        float* __restrict__ out,
                        int M, int N, int K, int H) {
  __shared__ short sA[FTILE * FBK];
  __shared__ short sB[FTILE * FBK];

  const int tid  = threadIdx.x;
  const int lane = tid & 63;
  const int r16  = lane & 15;
  const int q    = lane >> 4;
  const int wave = tid >> 6;
  const int wm   = (wave & 1) * 64;
  const int wn   = (wave >> 1) * 64;
  const int m0   = blockIdx.y * FTILE;
  const int n0   = blockIdx.x * FTILE;

  f32x4 acc[4][4];
#pragma unroll
  for (int i = 0; i < 4; ++i)
#pragma unroll
    for (int j = 0; j < 4; ++j)
      acc[i][j] = (f32x4){0.f, 0.f, 0.f, 0.f};

  for (int k0 = 0; k0 < K; k0 += FBK) {
    __syncthreads();
#pragma unroll
    for (int it = 0; it < 4; ++it) {
      const int chunk = it * 256 + tid;
      const int row   = chunk >> 3;
      const int c     = chunk & 7;
      const int cs    = c ^ (row & 7);
      const float* gA = Af32 + (size_t)(m0 + row) * K + (k0 + cs * 8);
      const float* gB = Bf32 + (size_t)(n0 + row) * K + (k0 + cs * 8);
      float4 a0 = ((const float4*)gA)[0], a1 = ((const float4*)gA)[1];
      float4 b0 = ((const float4*)gB)[0], b1 = ((const float4*)gB)[1];
      short8 va, vb;
      va[0] = (short)f2bf(a0.x); va[1] = (short)f2bf(a0.y);
      va[2] = (short)f2bf(a0.z); va[3] = (short)f2bf(a0.w);
      va[4] = (short)f2bf(a1.x); va[5] = (short)f2bf(a1.y);
      va[6] = (short)f2bf(a1.z); va[7] = (short)f2bf(a1.w);
      vb[0] = (short)f2bf(b0.x); vb[1] = (short)f2bf(b0.y);
      vb[2] = (short)f2bf(b0.z); vb[3] = (short)f2bf(b0.w);
      vb[4] = (short)f2bf(b1.x); vb[5] = (short)f2bf(b1.y);
      vb[6] = (short)f2bf(b1.z); vb[7] = (short)f2bf(b1.w);
      *(short8*)&sA[chunk * 8] = va;
      *(short8*)&sB[chunk * 8] = vb;
    }
    __syncthreads();

#pragma unroll
    for (int ks = 0; ks < 2; ++ks) {
      short8 af[4], bfr[4];
#pragma unroll
      for (int i = 0; i < 4; ++i) {
        const int row = wm + i * 16 + r16;
        const int cc  = ks * 4 + q;
        af[i] = *(const short8*)&sA[row * FBK + (cc ^ (row & 7)) * 8];
      }
#pragma unroll
      for (int j = 0; j < 4; ++j) {
        const int row = wn + j * 16 + r16;
        const int cc  = ks * 4 + q;
        bfr[j] = *(const short8*)&sB[row * FBK + (cc ^ (row & 7)) * 8];
      }
#pragma unroll
      for (int i = 0; i < 4; ++i)
#pragma unroll
        for (int j = 0; j < 4; ++j)
          acc[i][j] = __builtin_amdgcn_mfma_f32_16x16x32_bf16(
              af[i], bfr[j], acc[i][j], 0, 0, 0);
    }
  }

  float bj[4];
#pragma unroll
  for (int j = 0; j < 4; ++j) bj[j] = bias[n0 + wn + j * 16 + r16];
  const size_t chunk_elems = (size_t)M * H;
#pragma unroll
  for (int j = 0; j < 4; ++j) {
    const int n  = n0 + wn + j * 16 + r16;
    const int ci = n / H;
    const int h  = n - ci * H;
    float* obase = out + (size_t)ci * chunk_elems + h;
#pragma unroll
    for (int i = 0; i < 4; ++i) {
      const int mb = m0 + wm + i * 16 + q * 4;
#pragma unroll
      for (int rr = 0; rr < 4; ++rr) {
        obase[(size_t)(mb + rr) * H] = acc[i][j][rr] + bj[j];
      }
    }
  }
}

extern "C" void kernel_launch(void* const* d_in, const int* in_sizes, int n_in,
                              void* d_out, int out_size, void* d_ws, size_t ws_size,
                              hipStream_t stream) {
  const float* x = (const float*)d_in[0];
  const float* W = (const float*)d_in[1];
  const float* b = (const float*)d_in[2];
  float* out = (float*)d_out;

  const int N = in_sizes[2];                 // 12288
  const int K = in_sizes[1] / N;             // 4096
  const int M = in_sizes[0] / K;             // 8192 (= 4*2048)
  const int H = N / 3;                       // 4096

  const size_t nA = (size_t)M * K;
  const size_t nB = (size_t)N * K;
  const bool ws_ok = ws_size >= (nA + nB) * sizeof(unsigned short);
  const bool big   = ws_ok && (M % BM == 0) && (N % BN == 0) &&
                     (K % BKT == 0) && (K / BKT >= 4);

  if (big) {
    unsigned short* xa = (unsigned short*)d_ws;
    unsigned short* wb = xa + nA;
    const long long nA8 = (long long)(nA / 8);
    const long long nB8 = (long long)(nB / 8);
    const long long tot = nA8 + nB8;
    cast2_f32_to_bf16<<<(int)((tot + 255) / 256), 256, 0, stream>>>(
        x, xa, nA8, W, wb, nB8);
    const int nblocks = (M / BM) * (N / BN); // 32 * 48 = 1536
    gemm256_bias_split<<<nblocks, 512, 0, stream>>>(xa, wb, b, out, M, N, K, H);
  } else {
    dim3 grid(N / FTILE, M / FTILE);
    gemm_bias_split_fb<<<grid, 256, 0, stream>>>(x, W, b, out, M, N, K, H);
  }
}

// Round 5
// 1245.068 us; speedup vs baseline: 1.4002x; 1.1287x over previous
//
#include <hip/hip_runtime.h>
#include <stdint.h>

// ---------------------------------------------------------------------------
// Fused concat-linear: y = x @ W^T + b, x:[8192,4096] f32, W:[12288,4096] f32,
// b:[12288]. Output = 3 chunks of [8192,4096] f32 concatenated flat.
// v6: K-loop frozen at v5 (proven 256x256 2-barrier lockstep + 2-level
// L2-coop swizzle, 900us). New: (1) LDS-transposed float4 epilogue (256B
// contiguous segments, kills the 26% write amplification of 4B scalar
// stores); (2) dense grid-stride cast kernel (1 float4/iter, uint2 out).
// ---------------------------------------------------------------------------

typedef __attribute__((ext_vector_type(8))) short short8;   // 8 x bf16 (4 VGPR)
typedef __attribute__((ext_vector_type(4))) float f32x4;    // MFMA C/D

#define BM  256
#define BN  256
#define BKT 64    // K-tile depth in bf16: 8 chunks of 16 B per row

// round-to-nearest-even f32 -> bf16 (bit trick; inputs are finite normals)
__device__ __forceinline__ unsigned short f2bf(float f) {
  union { float f; unsigned u; } v; v.f = f;
  unsigned u = v.u;
  u += 0x7FFFu + ((u >> 16) & 1u);
  return (unsigned short)(u >> 16);
}

// grid-stride cast: one float4 load (16B, lane-dense) -> one uint2 store (8B)
__global__ __launch_bounds__(256)
void cast_all_f32_to_bf16(const float* __restrict__ a, unsigned long long na4,
                          unsigned short* __restrict__ oa,
                          const float* __restrict__ b, unsigned long long nb4,
                          unsigned short* __restrict__ ob) {
  const unsigned long long stride = (unsigned long long)gridDim.x * blockDim.x;
  const unsigned long long i0 = (unsigned long long)blockIdx.x * blockDim.x + threadIdx.x;
  for (unsigned long long k = i0; k < na4; k += stride) {
    float4 v = ((const float4*)a)[k];
    uint2 o;
    o.x = (unsigned)f2bf(v.x) | ((unsigned)f2bf(v.y) << 16);
    o.y = (unsigned)f2bf(v.z) | ((unsigned)f2bf(v.w) << 16);
    ((uint2*)oa)[k] = o;
  }
  for (unsigned long long k = i0; k < nb4; k += stride) {
    float4 v = ((const float4*)b)[k];
    uint2 o;
    o.x = (unsigned)f2bf(v.x) | ((unsigned)f2bf(v.y) << 16);
    o.y = (unsigned)f2bf(v.z) | ((unsigned)f2bf(v.w) << 16);
    ((uint2*)ob)[k] = o;
  }
}

__device__ __forceinline__ void gload16(const unsigned short* src, short* dst) {
  __builtin_amdgcn_global_load_lds(
      (const __attribute__((address_space(1))) unsigned int*)src,
      (__attribute__((address_space(3))) unsigned int*)dst, 16, 0, 0);
}

// ---------------------------------------------------------------------------
// 256x256 kernel (v5 K-loop, unchanged). 512 threads = 8 waves (2M x 4N),
// each wave owns a 128x64 C sub-tile (acc[8][4] f32x4). LDS: 128 KiB single
// block per CU. Per K-tile j (buffer P=j&1), 4 phases, each {reads; stage 1
// unit; barrier; lgkm(0); setprio(1); 16 MFMA; setprio(0); barrier};
// vmcnt(6) at tile end drains exactly tile j+1's 8 loads. Proven @900us.
// Epilogue: LDS-transpose (2 passes x 16KB/wave) -> float4 stores in 256B
// row segments.
// ---------------------------------------------------------------------------
__global__ __launch_bounds__(512, 2)
void gemm256_bias_split(const unsigned short* __restrict__ A,   // [M][K] bf16
                        const unsigned short* __restrict__ B,   // [N][K] bf16
                        const float* __restrict__ bias,         // [N]
                        float* __restrict__ out,                // 3 x [M][H]
                        int M, int N, int K, int H) {
  __shared__ short smem[2 * BM * BKT + 2 * BN * BKT];   // 128 KiB
  short* const sA0 = smem;                  // sA(buf) = sA0 + buf*BM*BKT
  short* const sB0 = smem + 2 * BM * BKT;   // sB(buf) = sB0 + buf*BN*BKT

  const int tid  = threadIdx.x;
  const int lane = tid & 63;
  const int r16  = lane & 15;
  const int q    = lane >> 4;
  const int wave = tid >> 6;
  const int wr   = wave >> 2;          // 0..1
  const int wc   = wave & 3;           // 0..3
  const int AR   = wr * 128;
  const int BR   = wc * 64;

  // ---- two-level L2-cooperative swizzle (v5, kept) ----
  const int ntx = N / BN;
  const int nwg = gridDim.x;
  const int mty = nwg / ntx;
  int bid = blockIdx.x;
  int m0, n0;
  if ((nwg & 7) == 0 && (mty & 7) == 0) {
    const int GM  = mty >> 3;          // m-panels per XCD (4 here)
    const int xcd = bid & 7;
    const int l   = bid >> 3;          // local index within XCD chunk
    const int lm  = l % GM;
    const int ln  = l / GM;            // 0..ntx-1
    m0 = (xcd * GM + lm) * BM;
    n0 = ln * BN;
  } else if ((nwg & 7) == 0) {
    const int cpx = nwg >> 3;
    const int b2  = (bid & 7) * cpx + (bid >> 3);
    n0 = (b2 % ntx) * BN;
    m0 = (b2 / ntx) * BM;
  } else {
    n0 = (bid % ntx) * BN;
    m0 = (bid / ntx) * BM;
  }

  const int NT = K / BKT;

  // ---- staging geometry (per thread): one 16B chunk per issue ----
  const int c   = tid & 7;                       // chunk within row
  const int pr  = tid >> 3;                      // 0..63
  const int csz = c ^ (pr & 7);                  // pre-swizzled source chunk
  const unsigned short* gA = A + (size_t)(m0 + pr) * K + csz * 8;
  const int prB = (pr & 31) + ((tid >> 8) << 6); // B row interleave
  const unsigned short* gB = B + (size_t)(n0 + prB) * K + csz * 8;
  const int dA = pr * 64 + c * 8;                // shorts into sA(buf)
  const int dB = prB * 64 + c * 8;
  const size_t K128 = (size_t)128 * K;

  auto stageA = [&](int buf, int kt, int u) {    // unit u: rows {64u.., 128+64u..}
    const unsigned short* s = gA + (size_t)(u * 64) * K + kt * BKT;
    short* d = sA0 + buf * (BM * BKT) + dA + u * 4096;
    gload16(s, d);
    gload16(s + K128, d + 8192);
  };
  auto stageB = [&](int buf, int kt, int u) {    // unit u: rows {32u + 64k ..}
    const unsigned short* s = gB + (size_t)(u * 32) * K + kt * BKT;
    short* d = sB0 + buf * (BN * BKT) + dB + u * 2048;
    gload16(s, d);
    gload16(s + K128, d + 8192);
  };

  // ---- ds_read geometry: frag(row = base + f*16 + r16, chunk = ks*4 + q),
  //      chunk XOR-unswizzled by (row&7) == (r16&7) ----
  const int swz  = r16 & 7;
  const int aoff = (AR + r16) * 64;
  const int boff = (BR + r16) * 64;
  const int ck0  = (q ^ swz) * 8;                // ks=0
  const int ck1  = ((4 + q) ^ swz) * 8;          // ks=1

  f32x4 acc[8][4];
#pragma unroll
  for (int i = 0; i < 8; ++i)
#pragma unroll
    for (int j = 0; j < 4; ++j) acc[i][j] = (f32x4){0.f, 0.f, 0.f, 0.f};

  // ---- prologue: stream t0.{Au0,Bu0,Au1,Bu1}, t1.{Au0,Bu0,Au1} ----
  stageA(0, 0, 0); stageB(0, 0, 0); stageA(0, 0, 1); stageB(0, 0, 1);
  stageA(1, 1, 0); stageB(1, 1, 0); stageA(1, 1, 1);
  asm volatile("s_waitcnt vmcnt(6)" ::: "memory");   // t0 fully landed
  __builtin_amdgcn_s_barrier();

  short8 alo[4][2], ahi[4][2], b01[2][2], b23[2][2];

  for (int j = 0; j < NT; ++j) {
    const int P = j & 1;
    const short* bA = sA0 + P * (BM * BKT);
    const short* bB = sB0 + P * (BN * BKT);

    // ===== phase 1: read A m0-3 + B n0-1 ; stage (j+1).Bu1 =====
#pragma unroll
    for (int mf = 0; mf < 4; ++mf) {
      alo[mf][0] = *(const short8*)&bA[aoff + mf * 1024 + ck0];
      alo[mf][1] = *(const short8*)&bA[aoff + mf * 1024 + ck1];
    }
#pragma unroll
    for (int nf = 0; nf < 2; ++nf) {
      b01[nf][0] = *(const short8*)&bB[boff + nf * 1024 + ck0];
      b01[nf][1] = *(const short8*)&bB[boff + nf * 1024 + ck1];
    }
    if (j + 1 < NT) stageB(P ^ 1, j + 1, 1);
    __builtin_amdgcn_s_barrier();
    asm volatile("s_waitcnt lgkmcnt(0)" ::: "memory");
    __builtin_amdgcn_sched_barrier(0);
    __builtin_amdgcn_s_setprio(1);
#pragma unroll
    for (int mf = 0; mf < 4; ++mf)
#pragma unroll
      for (int nf = 0; nf < 2; ++nf) {
        acc[mf][nf] = __builtin_amdgcn_mfma_f32_16x16x32_bf16(alo[mf][0], b01[nf][0], acc[mf][nf], 0, 0, 0);
        acc[mf][nf] = __builtin_amdgcn_mfma_f32_16x16x32_bf16(alo[mf][1], b01[nf][1], acc[mf][nf], 0, 0, 0);
      }
    __builtin_amdgcn_s_setprio(0);
    __builtin_amdgcn_s_barrier();

    // ===== phase 2: read B n2-3 ; stage (j+2).Au0 =====
#pragma unroll
    for (int nf = 0; nf < 2; ++nf) {
      b23[nf][0] = *(const short8*)&bB[boff + (nf + 2) * 1024 + ck0];
      b23[nf][1] = *(const short8*)&bB[boff + (nf + 2) * 1024 + ck1];
    }
    if (j + 2 < NT) stageA(P, j + 2, 0);
    __builtin_amdgcn_s_barrier();
    asm volatile("s_waitcnt lgkmcnt(0)" ::: "memory");
    __builtin_amdgcn_sched_barrier(0);
    __builtin_amdgcn_s_setprio(1);
#pragma unroll
    for (int mf = 0; mf < 4; ++mf)
#pragma unroll
      for (int nf = 0; nf < 2; ++nf) {
        acc[mf][nf + 2] = __builtin_amdgcn_mfma_f32_16x16x32_bf16(alo[mf][0], b23[nf][0], acc[mf][nf + 2], 0, 0, 0);
        acc[mf][nf + 2] = __builtin_amdgcn_mfma_f32_16x16x32_bf16(alo[mf][1], b23[nf][1], acc[mf][nf + 2], 0, 0, 0);
      }
    __builtin_amdgcn_s_setprio(0);
    __builtin_amdgcn_s_barrier();

    // ===== phase 3: read A m4-7 ; stage (j+2).Bu0 =====
#pragma unroll
    for (int mf = 0; mf < 4; ++mf) {
      ahi[mf][0] = *(const short8*)&bA[aoff + (mf + 4) * 1024 + ck0];
      ahi[mf][1] = *(const short8*)&bA[aoff + (mf + 4) * 1024 + ck1];
    }
    if (j + 2 < NT) stageB(P, j + 2, 0);
    __builtin_amdgcn_s_barrier();
    asm volatile("s_waitcnt lgkmcnt(0)" ::: "memory");
    __builtin_amdgcn_sched_barrier(0);
    __builtin_amdgcn_s_setprio(1);
#pragma unroll
    for (int mf = 0; mf < 4; ++mf)
#pragma unroll
      for (int nf = 0; nf < 2; ++nf) {
        acc[mf + 4][nf + 2] = __builtin_amdgcn_mfma_f32_16x16x32_bf16(ahi[mf][0], b23[nf][0], acc[mf + 4][nf + 2], 0, 0, 0);
        acc[mf + 4][nf + 2] = __builtin_amdgcn_mfma_f32_16x16x32_bf16(ahi[mf][1], b23[nf][1], acc[mf + 4][nf + 2], 0, 0, 0);
      }
    __builtin_amdgcn_s_setprio(0);
    __builtin_amdgcn_s_barrier();

    // ===== phase 4: stage (j+2).Au1 ; MFMA (m4-7 x n0-1) ; vmcnt(6) =====
    if (j + 2 < NT) stageA(P, j + 2, 1);
    __builtin_amdgcn_s_barrier();
    __builtin_amdgcn_s_setprio(1);
#pragma unroll
    for (int mf = 0; mf < 4; ++mf)
#pragma unroll
      for (int nf = 0; nf < 2; ++nf) {
        acc[mf + 4][nf] = __builtin_amdgcn_mfma_f32_16x16x32_bf16(ahi[mf][0], b01[nf][0], acc[mf + 4][nf], 0, 0, 0);
        acc[mf + 4][nf] = __builtin_amdgcn_mfma_f32_16x16x32_bf16(ahi[mf][1], b01[nf][1], acc[mf + 4][nf], 0, 0, 0);
      }
    __builtin_amdgcn_s_setprio(0);
    if (j < NT - 2) asm volatile("s_waitcnt vmcnt(6)" ::: "memory");
    else            asm volatile("s_waitcnt vmcnt(0)" ::: "memory");
    __builtin_amdgcn_s_barrier();
  }

  // ---- epilogue: LDS-transposed +bias, float4 stores (256B segments) ----
  // C element (m0+AR + mf*16+q*4+rr, n0+BR + nf*16+r16) = acc[mf][nf][rr].
  // Each wave's 64-col range lies in ONE output chunk (BR,H multiples of 64).
  float bj[4];
#pragma unroll
  for (int nf = 0; nf < 4; ++nf) bj[nf] = bias[n0 + BR + nf * 16 + r16];
  const int nb = n0 + BR;
  const int ci = nb / H;
  const int h0 = nb - ci * H;
  float* const obase = out + (size_t)ci * ((size_t)M * H) + h0;
  const int mbase = m0 + AR;
  float* const T = reinterpret_cast<float*>(smem) + wave * 4096;  // 16KB/wave

#pragma unroll
  for (int p = 0; p < 2; ++p) {
    // write half the subtile: T[row][col], row=mf*16+q*4+rr (0..63), col 0..63
#pragma unroll
    for (int mf = 0; mf < 4; ++mf)
#pragma unroll
      for (int nf = 0; nf < 4; ++nf)
#pragma unroll
        for (int rr = 0; rr < 4; ++rr)
          T[(mf * 16 + q * 4 + rr) * 64 + nf * 16 + r16] =
              acc[p * 4 + mf][nf][rr] + bj[nf];
    asm volatile("s_waitcnt lgkmcnt(0)" ::: "memory");  // wave-private region
    // read back row-major float4: inst i covers rows i*4..i*4+3, 256B/row
#pragma unroll
    for (int i = 0; i < 16; ++i) {
      const int row = i * 4 + q;
      float4 v = *(const float4*)&T[row * 64 + r16 * 4];
      *(float4*)&obase[(size_t)(mbase + p * 64 + row) * H + r16 * 4] = v;
    }
    asm volatile("s_waitcnt lgkmcnt(0)" ::: "memory");  // drain before reuse
  }
}

// ---------------------------------------------------------------------------
// Fallback (no workspace / odd shapes): 128x128 kernel, f32 inputs staged via
// VGPR round-trip with inline f32->bf16.
// ---------------------------------------------------------------------------
#define FTILE 128
#define FBK   64

__global__ __launch_bounds__(256)
void gemm_bias_split_fb(const float* __restrict__ Af32,
                        const float* __restrict__ Bf32,
                        const float* __restrict__ bias,
                        float* __restrict__ out,
                        int M, int N, int K, int H) {
  __shared__ short sA[FTILE * FBK];
  __shared__ short sB[FTILE * FBK];

  const int tid  = threadIdx.x;
  const int lane = tid & 63;
  const int r16  = lane & 15;
  const int q    = lane >> 4;
  const int wave = tid >> 6;
  const int wm   = (wave & 1) * 64;
  const int wn   = (wave >> 1) * 64;
  const int m0   = blockIdx.y * FTILE;
  const int n0   = blockIdx.x * FTILE;

  f32x4 acc[4][4];
#pragma unroll
  for (int i = 0; i < 4; ++i)
#pragma unroll
    for (int j = 0; j < 4; ++j)
      acc[i][j] = (f32x4){0.f, 0.f, 0.f, 0.f};

  for (int k0 = 0; k0 < K; k0 += FBK) {
    __syncthreads();
#pragma unroll
    for (int it = 0; it < 4; ++it) {
      const int chunk = it * 256 + tid;
      const int row   = chunk >> 3;
      const int c     = chunk & 7;
      const int cs    = c ^ (row & 7);
      const float* gA = Af32 + (size_t)(m0 + row) * K + (k0 + cs * 8);
      const float* gB = Bf32 + (size_t)(n0 + row) * K + (k0 + cs * 8);
      float4 a0 = ((const float4*)gA)[0], a1 = ((const float4*)gA)[1];
      float4 b0 = ((const float4*)gB)[0], b1 = ((const float4*)gB)[1];
      short8 va, vb;
      va[0] = (short)f2bf(a0.x); va[1] = (short)f2bf(a0.y);
      va[2] = (short)f2bf(a0.z); va[3] = (short)f2bf(a0.w);
      va[4] = (short)f2bf(a1.x); va[5] = (short)f2bf(a1.y);
      va[6] = (short)f2bf(a1.z); va[7] = (short)f2bf(a1.w);
      vb[0] = (short)f2bf(b0.x); vb[1] = (short)f2bf(b0.y);
      vb[2] = (short)f2bf(b0.z); vb[3] = (short)f2bf(b0.w);
      vb[4] = (short)f2bf(b1.x); vb[5] = (short)f2bf(b1.y);
      vb[6] = (short)f2bf(b1.z); vb[7] = (short)f2bf(b1.w);
      *(short8*)&sA[chunk * 8] = va;
      *(short8*)&sB[chunk * 8] = vb;
    }
    __syncthreads();

#pragma unroll
    for (int ks = 0; ks < 2; ++ks) {
      short8 af[4], bfr[4];
#pragma unroll
      for (int i = 0; i < 4; ++i) {
        const int row = wm + i * 16 + r16;
        const int cc  = ks * 4 + q;
        af[i] = *(const short8*)&sA[row * FBK + (cc ^ (row & 7)) * 8];
      }
#pragma unroll
      for (int j = 0; j < 4; ++j) {
        const int row = wn + j * 16 + r16;
        const int cc  = ks * 4 + q;
        bfr[j] = *(const short8*)&sB[row * FBK + (cc ^ (row & 7)) * 8];
      }
#pragma unroll
      for (int i = 0; i < 4; ++i)
#pragma unroll
        for (int j = 0; j < 4; ++j)
          acc[i][j] = __builtin_amdgcn_mfma_f32_16x16x32_bf16(
              af[i], bfr[j], acc[i][j], 0, 0, 0);
    }
  }

  float bj[4];
#pragma unroll
  for (int j = 0; j < 4; ++j) bj[j] = bias[n0 + wn + j * 16 + r16];
  const size_t chunk_elems = (size_t)M * H;
#pragma unroll
  for (int j = 0; j < 4; ++j) {
    const int n  = n0 + wn + j * 16 + r16;
    const int ci = n / H;
    const int h  = n - ci * H;
    float* obase = out + (size_t)ci * chunk_elems + h;
#pragma unroll
    for (int i = 0; i < 4; ++i) {
      const int mb = m0 + wm + i * 16 + q * 4;
#pragma unroll
      for (int rr = 0; rr < 4; ++rr) {
        obase[(size_t)(mb + rr) * H] = acc[i][j][rr] + bj[j];
      }
    }
  }
}

extern "C" void kernel_launch(void* const* d_in, const int* in_sizes, int n_in,
                              void* d_out, int out_size, void* d_ws, size_t ws_size,
                              hipStream_t stream) {
  const float* x = (const float*)d_in[0];
  const float* W = (const float*)d_in[1];
  const float* b = (const float*)d_in[2];
  float* out = (float*)d_out;

  const int N = in_sizes[2];                 // 12288
  const int K = in_sizes[1] / N;             // 4096
  const int M = in_sizes[0] / K;             // 8192 (= 4*2048)
  const int H = N / 3;                       // 4096

  const size_t nA = (size_t)M * K;
  const size_t nB = (size_t)N * K;
  const bool ws_ok = ws_size >= (nA + nB) * sizeof(unsigned short);
  const bool big   = ws_ok && (M % BM == 0) && (N % BN == 0) &&
                     (K % BKT == 0) && (K / BKT >= 4) && ((H & 63) == 0);

  if (big) {
    unsigned short* xa = (unsigned short*)d_ws;
    unsigned short* wb = xa + nA;
    cast_all_f32_to_bf16<<<2048, 256, 0, stream>>>(
        x, (unsigned long long)(nA / 4), xa,
        W, (unsigned long long)(nB / 4), wb);
    const int nblocks = (M / BM) * (N / BN); // 32 * 48 = 1536
    gemm256_bias_split<<<nblocks, 512, 0, stream>>>(xa, wb, b, out, M, N, K, H);
  } else {
    dim3 grid(N / FTILE, M / FTILE);
    gemm_bias_split_fb<<<grid, 256, 0, stream>>>(x, W, b, out, M, N, K, H);
  }
}